// Round 8
// baseline (154.733 us; speedup 1.0000x reference)
//
#include <hip/hip_runtime.h>
#include <stdint.h>

// RandomSelfAttention: B=2, S=4096, S2=2048, NH=8, H=64, NKEYS=64
// q:(B,S2,NH,H) f32, k/v:(B,S,NH,H) f32, idx:(B,S2,NKEYS) int
// out z:(B,S2,NH,H) f32
//
// One wave per (b,q,n); 128-thread blocks (2 waves), per-wave 16KB LDS
// buffer reused k->v. Gather via global_load_lds width=16 (fire-and-forget
// DMA, no dest VGPRs) so ALL 16 row-loads are in flight per wall — rounds
// 4-7 proved the compiler refuses to hold a 16xfloat4 register batch
// (VGPR pinned ~60, ~4 loads in flight, dur stuck at 60us, no pipe >36%).
// m104 layout constraint: DMA writes lds_base + lane*16, so lane (g,hc)
// fetches row offs[it*4+g] chunk hc -> rows contiguous at it*1024; read
// back lane-linear ds_read_b128 (standard ~12cyc pattern, m134).
// v DMAs issued BEFORE softmax: v latency hides under ~150 VALU softmax ops.
// Barriers provide the vmcnt/lgkmcnt drains (m97-verified pattern).
// Block swizzle: blockIdx%16 = (b,n) combo -> per-XCD L2 working set ~4MB.
//
// Round 3 lesson: never cap regs to 64 (spill = 750MB scratch). Watch
// WRITE_SIZE (8MB = clean) on any edit.

#define BB 2
#define SS 4096
#define S2V 2048
#define NHV 8
#define HV 64
#define NKV 64

__device__ __forceinline__ void async16(const float* g, float* l) {
    __builtin_amdgcn_global_load_lds(
        (const __attribute__((address_space(1))) void*)g,
        (__attribute__((address_space(3))) void*)l,
        16, 0, 0);
}

__global__ __launch_bounds__(128)
void rsa_kernel(const float* __restrict__ q, const float* __restrict__ k,
                const float* __restrict__ v, const int* __restrict__ idx,
                float* __restrict__ out) {
    const int lane = threadIdx.x & 63;
    const int w    = threadIdx.x >> 6;
    const int bi   = blockIdx.x;

    const int combo = bi & 15;
    const int b     = combo >> 3;
    const int n     = combo & 7;
    const int qi    = ((bi >> 4) << 1) + w;

    const int g  = lane >> 4;    // key group 0..3
    const int hc = lane & 15;    // h-chunk 0..15 (float4 granularity)

    __shared__ float buf[2][4096];          // 16KB per wave
    float* mybuf = &buf[w][0];

    const size_t bq = (size_t)b * S2V + qi;

    // q chunk for this lane (prescaled by h^-0.5 = 1/8)
    const float* qrow = q + (bq * NHV + n) * HV;
    const float4 qv = *(const float4*)(qrow + hc * 4);
    const float4 q4 = make_float4(qv.x * 0.125f, qv.y * 0.125f,
                                  qv.z * 0.125f, qv.w * 0.125f);

    const int my_off = idx[bq * NKV + lane] * (NHV * HV);

    const float* kb = k + ((size_t)b * SS * NHV + n) * HV;
    const float* vb = v + ((size_t)b * SS * NHV + n) * HV;

    // ---- stage ALL 16 k-row quads via LDS-DMA (no dest regs: 16 in flight) ----
#pragma unroll
    for (int it = 0; it < 16; ++it) {
        const int off = __shfl(my_off, it * 4 + g, 64);   // key (it*4+g)'s row
        async16(kb + off + hc * 4, mybuf + it * 256);     // lane writes +lane*16B
    }
    __syncthreads();   // drains vmcnt -> k resident in LDS

    // ---- dots + butterflies from LDS (lane-linear b128 reads) ----
    float sc[16];
#pragma unroll
    for (int it = 0; it < 16; ++it) {
        const float4 k4 = *(const float4*)(mybuf + it * 256 + lane * 4);
        float d = k4.x * q4.x + k4.y * q4.y + k4.z * q4.z + k4.w * q4.w;
        d += __shfl_xor(d, 1);
        d += __shfl_xor(d, 2);
        d += __shfl_xor(d, 4);
        d += __shfl_xor(d, 8);
        sc[it] = d;   // full dot of key it*4+g, replicated over 16-lane group
    }
    __syncthreads();   // drains lgkmcnt -> safe to overwrite buffer with v

    // ---- stage ALL 16 v-row quads; latency hides under softmax below ----
#pragma unroll
    for (int it = 0; it < 16; ++it) {
        const int off = __shfl(my_off, it * 4 + g, 64);
        async16(vb + off + hc * 4, mybuf + it * 256);
    }

    // ---- softmax over 64 keys (registers only, no memory dependence) ----
    float m = sc[0];
#pragma unroll
    for (int it = 1; it < 16; ++it) m = fmaxf(m, sc[it]);
    m = fmaxf(m, __shfl_xor(m, 16));
    m = fmaxf(m, __shfl_xor(m, 32));

    float ssum = 0.f;
#pragma unroll
    for (int it = 0; it < 16; ++it) {
        sc[it] = __expf(sc[it] - m);
        ssum += sc[it];
    }
    ssum += __shfl_xor(ssum, 16);
    ssum += __shfl_xor(ssum, 32);
    const float rs = __frcp_rn(ssum);

    __syncthreads();   // drains vmcnt -> v resident in LDS

    // ---- z = sum_key p[key] * v_row[key] ----
    float4 z = make_float4(0.f, 0.f, 0.f, 0.f);
#pragma unroll
    for (int it = 0; it < 16; ++it) {
        const float4 v4 = *(const float4*)(mybuf + it * 256 + lane * 4);
        const float p = sc[it];
        z.x = fmaf(p, v4.x, z.x);
        z.y = fmaf(p, v4.y, z.y);
        z.z = fmaf(p, v4.z, z.z);
        z.w = fmaf(p, v4.w, z.w);
    }
    // reduce partial z across the 4 key groups
    z.x += __shfl_xor(z.x, 16); z.y += __shfl_xor(z.y, 16);
    z.z += __shfl_xor(z.z, 16); z.w += __shfl_xor(z.w, 16);
    z.x += __shfl_xor(z.x, 32); z.y += __shfl_xor(z.y, 32);
    z.z += __shfl_xor(z.z, 32); z.w += __shfl_xor(z.w, 32);

    if (g == 0) {
        float4 zo = make_float4(z.x * rs, z.y * rs, z.z * rs, z.w * rs);
        *(float4*)(out + (bq * NHV + n) * HV + hc * 4) = zo;
    }
}

extern "C" void kernel_launch(void* const* d_in, const int* in_sizes, int n_in,
                              void* d_out, int out_size, void* d_ws, size_t ws_size,
                              hipStream_t stream) {
    const float* q   = (const float*)d_in[0];
    const float* k   = (const float*)d_in[1];
    const float* v   = (const float*)d_in[2];
    const int*   idx = (const int*)d_in[3];
    float*       out = (float*)d_out;

    const int n_units = BB * S2V * NHV;       // 32768 waves
    const int blocks  = n_units / 2;          // 16384 blocks of 2 waves
    rsa_kernel<<<blocks, 128, 0, stream>>>(q, k, v, idx, out);
}

// Round 9
// 113.507 us; speedup vs baseline: 1.3632x; 1.3632x over previous
//
#include <hip/hip_runtime.h>
#include <stdint.h>

// RandomSelfAttention: B=2, S=4096, S2=2048, NH=8, H=64, NKEYS=64
// q:(B,S2,NH,H) f32, k/v:(B,S,NH,H) f32, idx:(B,S2,NKEYS) int
// out z:(B,S2,NH,H) f32
//
// MODEL (fit across rounds 2-8): dur == gather-line count / (0.5 lines/cyc/CU).
// Scheduling (reg batches r5/r6, tier pin r7, LDS-DMA r8) never moved it;
// only line count does (r2->r4: 1300->524 lines/wave, 127->60us). So this
// round halves lines: prepass converts k/v to fp16 in d_ws (streaming,
// coalesced, ~8us), gather reads 128B fp16 rows = 2 lines instead of 4.
// Lane map: 8 lanes/row x 16B (half8); 8 VMEM instr/phase x 16 lines.
// Fallback to fp32 kernel if ws_size too small.
//
// Round 3 lesson: never cap regs to 64 (spill = 750MB scratch traffic).
// Round 8 lesson: 32KB LDS/block chokes occupancy to 20% — stay LDS-free.
// Watch WRITE_SIZE (main should stay 8MB) for spills on any edit.
// Block swizzle: blockIdx%16 = (b,n) combo -> per-XCD L2 working set ~4MB
// (fp16: ~2MB).

#define BB 2
#define SS 4096
#define S2V 2048
#define NHV 8
#define HV 64
#define NKV 64

typedef _Float16 half_t;
typedef _Float16 half8 __attribute__((ext_vector_type(8)));

#define NE ((size_t)BB * SS * NHV * HV)   // 4,194,304 elements in k (and v)

// ---- prepass: k,v fp32 -> fp16 into workspace (coalesced stream) ----
__global__ __launch_bounds__(256)
void cvt_kernel(const float* __restrict__ k, const float* __restrict__ v,
                half_t* __restrict__ kh, half_t* __restrict__ vh) {
    const size_t base = ((size_t)blockIdx.x * 256 + threadIdx.x) * 8;
    const float* src; half_t* dst; size_t off;
    if (base < NE) { src = k; dst = kh; off = base; }
    else           { src = v; dst = vh; off = base - NE; }
    const float4 a = *(const float4*)(src + off);
    const float4 b = *(const float4*)(src + off + 4);
    half8 h = { (_Float16)a.x, (_Float16)a.y, (_Float16)a.z, (_Float16)a.w,
                (_Float16)b.x, (_Float16)b.y, (_Float16)b.z, (_Float16)b.w };
    *(half8*)(dst + off) = h;
}

// ---- main: fp16 gather path. Lane = (g=lane>>3 key group, hc=lane&7) ----
__global__ __launch_bounds__(256)
void rsa_fp16_kernel(const float* __restrict__ q, const half_t* __restrict__ kh,
                     const half_t* __restrict__ vh, const int* __restrict__ idx,
                     float* __restrict__ out) {
    const int lane = threadIdx.x & 63;
    const int w    = threadIdx.x >> 6;
    const int bi   = blockIdx.x;

    const int combo = bi & 15;
    const int b     = combo >> 3;
    const int n     = combo & 7;
    const int qi    = ((bi >> 4) << 2) + w;

    const int g  = lane >> 3;    // key group 0..7
    const int hc = lane & 7;     // h-chunk 0..7 (half8 = 16B granularity)

    const size_t bq = (size_t)b * S2V + qi;

    // q chunk: 8 floats (prescaled by h^-0.5 = 1/8)
    const float* qrow = q + (bq * NHV + n) * HV;
    const float4 qa = *(const float4*)(qrow + hc * 8);
    const float4 qb = *(const float4*)(qrow + hc * 8 + 4);
    float qf[8] = { qa.x * 0.125f, qa.y * 0.125f, qa.z * 0.125f, qa.w * 0.125f,
                    qb.x * 0.125f, qb.y * 0.125f, qb.z * 0.125f, qb.w * 0.125f };

    const int my_off = idx[bq * NKV + lane] * (NHV * HV);

    const half_t* kb = kh + ((size_t)b * SS * NHV + n) * HV;
    const half_t* vb = vh + ((size_t)b * SS * NHV + n) * HV;

    // ---- phase 1: scores. iter it covers keys it*8 + g (8 rows/instr) ----
    float sc[8];
#pragma unroll
    for (int it = 0; it < 8; ++it) {
        const int off = __shfl(my_off, it * 8 + g, 64);
        const half8 kk = *(const half8*)(kb + off + hc * 8);
        float d = 0.f;
#pragma unroll
        for (int j = 0; j < 8; ++j) d = fmaf((float)kk[j], qf[j], d);
        d += __shfl_xor(d, 1);
        d += __shfl_xor(d, 2);
        d += __shfl_xor(d, 4);
        sc[it] = d;   // full dot of key it*8+g, replicated over 8-lane group
    }

    // ---- softmax over 64 keys ----
    float m = sc[0];
#pragma unroll
    for (int it = 1; it < 8; ++it) m = fmaxf(m, sc[it]);
    m = fmaxf(m, __shfl_xor(m, 8));
    m = fmaxf(m, __shfl_xor(m, 16));
    m = fmaxf(m, __shfl_xor(m, 32));

    float ssum = 0.f;
#pragma unroll
    for (int it = 0; it < 8; ++it) {
        sc[it] = __expf(sc[it] - m);
        ssum += sc[it];
    }
    ssum += __shfl_xor(ssum, 8);
    ssum += __shfl_xor(ssum, 16);
    ssum += __shfl_xor(ssum, 32);
    const float rs = __frcp_rn(ssum);

    // ---- phase 2: z = sum_key p[key] * v_row[key] ----
    float za[8] = {0.f, 0.f, 0.f, 0.f, 0.f, 0.f, 0.f, 0.f};
#pragma unroll
    for (int it = 0; it < 8; ++it) {
        const int off = __shfl(my_off, it * 8 + g, 64);
        const half8 vv = *(const half8*)(vb + off + hc * 8);
        const float p = sc[it];
#pragma unroll
        for (int j = 0; j < 8; ++j) za[j] = fmaf(p, (float)vv[j], za[j]);
    }
    // reduce partial z across the 8 key groups
#pragma unroll
    for (int j = 0; j < 8; ++j) {
        za[j] += __shfl_xor(za[j], 8);
        za[j] += __shfl_xor(za[j], 16);
        za[j] += __shfl_xor(za[j], 32);
    }

    if (g == 0) {
        float* orow = out + (bq * NHV + n) * HV + hc * 8;
        float4 o1 = make_float4(za[0] * rs, za[1] * rs, za[2] * rs, za[3] * rs);
        float4 o2 = make_float4(za[4] * rs, za[5] * rs, za[6] * rs, za[7] * rs);
        *(float4*)(orow)     = o1;
        *(float4*)(orow + 4) = o2;
    }
}

// ---- fallback (proven round-6 fp32 path) if ws too small ----
__global__ __launch_bounds__(256)
void rsa_fp32_kernel(const float* __restrict__ q, const float* __restrict__ k,
                     const float* __restrict__ v, const int* __restrict__ idx,
                     float* __restrict__ out) {
    const int lane = threadIdx.x & 63;
    const int w    = threadIdx.x >> 6;
    const int bi   = blockIdx.x;
    const int combo = bi & 15;
    const int b     = combo >> 3;
    const int n     = combo & 7;
    const int qi    = ((bi >> 4) << 2) + w;
    const int g  = lane >> 4;
    const int hc = lane & 15;
    const size_t bq = (size_t)b * S2V + qi;
    const float* qrow = q + (bq * NHV + n) * HV;
    const float4 qv = *(const float4*)(qrow + hc * 4);
    const float4 q4 = make_float4(qv.x * 0.125f, qv.y * 0.125f,
                                  qv.z * 0.125f, qv.w * 0.125f);
    const int my_off = idx[bq * NKV + lane] * (NHV * HV);
    const float* kb = k + ((size_t)b * SS * NHV + n) * HV;
    const float* vb = v + ((size_t)b * SS * NHV + n) * HV;
    float sc[16];
#pragma unroll
    for (int it = 0; it < 16; ++it) {
        const int off = __shfl(my_off, it * 4 + g, 64);
        const float4 k4 = *(const float4*)(kb + off + hc * 4);
        float d = k4.x * q4.x + k4.y * q4.y + k4.z * q4.z + k4.w * q4.w;
        d += __shfl_xor(d, 1);
        d += __shfl_xor(d, 2);
        d += __shfl_xor(d, 4);
        d += __shfl_xor(d, 8);
        sc[it] = d;
    }
    float m = sc[0];
#pragma unroll
    for (int it = 1; it < 16; ++it) m = fmaxf(m, sc[it]);
    m = fmaxf(m, __shfl_xor(m, 16));
    m = fmaxf(m, __shfl_xor(m, 32));
    float ssum = 0.f;
#pragma unroll
    for (int it = 0; it < 16; ++it) { sc[it] = __expf(sc[it] - m); ssum += sc[it]; }
    ssum += __shfl_xor(ssum, 16);
    ssum += __shfl_xor(ssum, 32);
    const float rs = __frcp_rn(ssum);
    float4 z = make_float4(0.f, 0.f, 0.f, 0.f);
#pragma unroll
    for (int it = 0; it < 16; ++it) {
        const int off = __shfl(my_off, it * 4 + g, 64);
        const float4 v4 = *(const float4*)(vb + off + hc * 4);
        const float p = sc[it];
        z.x = fmaf(p, v4.x, z.x); z.y = fmaf(p, v4.y, z.y);
        z.z = fmaf(p, v4.z, z.z); z.w = fmaf(p, v4.w, z.w);
    }
    z.x += __shfl_xor(z.x, 16); z.y += __shfl_xor(z.y, 16);
    z.z += __shfl_xor(z.z, 16); z.w += __shfl_xor(z.w, 16);
    z.x += __shfl_xor(z.x, 32); z.y += __shfl_xor(z.y, 32);
    z.z += __shfl_xor(z.z, 32); z.w += __shfl_xor(z.w, 32);
    if (g == 0) {
        float4 zo = make_float4(z.x * rs, z.y * rs, z.z * rs, z.w * rs);
        *(float4*)(out + (bq * NHV + n) * HV + hc * 4) = zo;
    }
}

extern "C" void kernel_launch(void* const* d_in, const int* in_sizes, int n_in,
                              void* d_out, int out_size, void* d_ws, size_t ws_size,
                              hipStream_t stream) {
    const float* q   = (const float*)d_in[0];
    const float* k   = (const float*)d_in[1];
    const float* v   = (const float*)d_in[2];
    const int*   idx = (const int*)d_in[3];
    float*       out = (float*)d_out;

    const int n_units = BB * S2V * NHV;       // 32768 waves
    const int blocks  = n_units / 4;          // 8192 blocks of 4 waves

    const size_t need = 2 * NE * sizeof(half_t);   // 16.8 MB
    if (ws_size >= need) {
        half_t* kh = (half_t*)d_ws;
        half_t* vh = kh + NE;
        const int cvt_blocks = (int)(2 * NE / 8 / 256);   // 4096
        cvt_kernel<<<cvt_blocks, 256, 0, stream>>>(k, v, kh, vh);
        rsa_fp16_kernel<<<blocks, 256, 0, stream>>>(q, kh, vh, idx, out);
    } else {
        rsa_fp32_kernel<<<blocks, 256, 0, stream>>>(q, k, v, idx, out);
    }
}